// Round 5
// baseline (264.645 us; speedup 1.0000x reference)
//
#include <hip/hip_runtime.h>
#include <math.h>

// MultiTaskGNN: 2-layer GAT + BN + ELU + two heads. N=50000, E=400000.
// R15: recovery round. R14's cooperative graph-build broke the harness
// (coop launch x graph capture) -> reverted to R13's 9-dispatch structure.
// Kept the one verified-safe piece of R14: split barrier drain in
// gemm_fullk (vmcnt(8) [own B, issued first, in-order retire] -> s_barrier
// [all B visible] -> vmcnt(0) [own A; A is strictly self-read]), so the 8
// A-loads stay in flight across the barrier. agg1/agg2/graph-build frozen
// from R13 (263.2us).

typedef unsigned short ushort_t;
typedef unsigned char uchar_t;
typedef __attribute__((ext_vector_type(8))) unsigned short ushort8;
typedef __attribute__((ext_vector_type(4))) unsigned short ushort4v;
typedef __attribute__((ext_vector_type(8))) short short8;
typedef __attribute__((ext_vector_type(4))) float f32x4;
typedef __attribute__((ext_vector_type(2))) float f32x2;

#define EPS_BN 1e-5f

__device__ __forceinline__ ushort_t f2bf(float f) {  // RNE
  unsigned u = __float_as_uint(f);
  unsigned r = u + 0x7fffu + ((u >> 16) & 1u);
  return (ushort_t)(r >> 16);
}
__device__ __forceinline__ float bf2f(ushort_t h) {
  return __uint_as_float((unsigned)h << 16);
}
__device__ __forceinline__ uchar_t f2fp8(float f) {  // e4m3 via HW cvt (RNE, sat)
  return (uchar_t)(__builtin_amdgcn_cvt_pk_fp8_f32(f, f, 0, false) & 0xff);
}
__device__ __forceinline__ float leaky02(float x) { return x >= 0.f ? x : 0.2f * x; }
__device__ __forceinline__ float elu_fast(float x) {
  return x > 0.f ? x : __expf(x) - 1.f;
}
__device__ __forceinline__ float wave_sum(float v) {
#pragma unroll
  for (int o = 1; o < 64; o <<= 1) v += __shfl_xor(v, o, 64);
  return v;
}
__device__ __forceinline__ int wave_incl_scan(int v, int lane) {
#pragma unroll
  for (int off = 1; off < 64; off <<= 1) {
    int t = __shfl_up(v, off, 64);
    if (lane >= off) v += t;
  }
  return v;
}

__device__ __forceinline__ void gld_lds16(const ushort_t* g, ushort_t* l) {
  __builtin_amdgcn_global_load_lds(
      (const __attribute__((address_space(1))) unsigned int*)g,
      (__attribute__((address_space(3))) unsigned int*)l, 16, 0, 0);
}

// ---------------- hist + fused x->bf16 cast ----------------
__global__ __launch_bounds__(256) void hist_kernel(
    const int* __restrict__ dst, int* __restrict__ counts, int E,
    const float* __restrict__ x, ushort_t* __restrict__ xb, int n8) {
  int e = blockIdx.x * blockDim.x + threadIdx.x;
  if (e < E) atomicAdd(&counts[dst[e]], 1);
  const int gsz = gridDim.x * blockDim.x;
  for (int j = e; j < n8; j += gsz) {
    float4 f0 = *(const float4*)(x + (size_t)j * 8);
    float4 f1 = *(const float4*)(x + (size_t)j * 8 + 4);
    ushort8 u;
    u[0] = f2bf(f0.x); u[1] = f2bf(f0.y); u[2] = f2bf(f0.z); u[3] = f2bf(f0.w);
    u[4] = f2bf(f1.x); u[5] = f2bf(f1.y); u[6] = f2bf(f1.z); u[7] = f2bf(f1.w);
    *(ushort8*)(xb + (size_t)j * 8) = u;
  }
}

// ---------------- scan chunks (256/block) + merged prep work ----------------
__global__ __launch_bounds__(256) void scan_chunks_kernel(
    const int* __restrict__ counts, int* __restrict__ offsets, int* __restrict__ partials,
    int N, int E, int* __restrict__ csr_src,
    const float* __restrict__ W1, const float* __restrict__ W2,
    ushort_t* __restrict__ W1t, ushort_t* __restrict__ W2t,
    const float* __restrict__ b1, const float* __restrict__ bn1w,
    const float* __restrict__ bn1b, const float* __restrict__ bn1m,
    const float* __restrict__ bn1v,
    const float* __restrict__ b2, const float* __restrict__ bn2w,
    const float* __restrict__ bn2b, const float* __restrict__ bn2m,
    const float* __restrict__ bn2v,
    float* __restrict__ S1, float* __restrict__ T1,
    float* __restrict__ S2, float* __restrict__ T2) {
  __shared__ int ws[4];
  const int tid = threadIdx.x, lane = tid & 63, wv = tid >> 6;
  const int i = blockIdx.x * 256 + tid;
  const int gsz = gridDim.x * 256;
  int v = (i < N) ? counts[i] : 0;
  int incl = wave_incl_scan(v, lane);
  if (lane == 63) ws[wv] = incl;
  __syncthreads();
  int wbase = 0;
  for (int k = 0; k < wv; ++k) wbase += ws[k];
  if (i < N) offsets[i] = wbase + incl - v;  // chunk-local exclusive
  if (tid == 255) partials[blockIdx.x] = wbase + incl;

  for (int j = i; j < 256 * 256; j += gsz) {
    int k = j >> 8, n2 = j & 255;
    W1t[n2 * 256 + k] = f2bf(W1[j]);
  }
  for (int j = i; j < 256 * 64; j += gsz) {
    int k = j >> 6, n2 = j & 63;
    W2t[n2 * 256 + k] = f2bf(W2[j]);
  }
  if (i < 256) {
    float s = bn1w[i] * rsqrtf(bn1v[i] + EPS_BN);
    S1[i] = s;
    T1[i] = (b1[i] - bn1m[i]) * s + bn1b[i];
  } else if (i < 320) {
    int j = i - 256;
    float s = bn2w[j] * rsqrtf(bn2v[j] + EPS_BN);
    S2[j] = s;
    T2[j] = (b2[j] - bn2m[j]) * s + bn2b[j];
  } else if (i < 384) {
    csr_src[E + i - 320] = 0;  // zero pad for unclamped tail loads
  }
}

// ---------------- scatter + inline pprefix scan + finalize offsets ----------------
__global__ __launch_bounds__(256) void scatter_kernel(
    const int* __restrict__ src, const int* __restrict__ dst,
    const int* __restrict__ offsets, const int* __restrict__ partials,
    int* __restrict__ cursor, int* __restrict__ csr_src,
    int* __restrict__ offs2, int E, int N, int nb) {
  __shared__ int pp[256];
  __shared__ int ws[4];
  __shared__ int tot;
  const int tid = threadIdx.x, lane = tid & 63, wv = tid >> 6;
  int v = (tid < nb) ? partials[tid] : 0;
  int incl = wave_incl_scan(v, lane);
  if (lane == 63) ws[wv] = incl;
  __syncthreads();
  int wbase = 0;
  for (int k = 0; k < wv; ++k) wbase += ws[k];
  pp[tid] = wbase + incl - v;
  if (tid == 255) tot = wbase + incl;
  __syncthreads();

  int idx = blockIdx.x * 256 + tid;
  if (idx < E) {
    int d = dst[idx];
    int p = atomicAdd(&cursor[d], 1);
    csr_src[offsets[d] + pp[d >> 8] + p] = src[idx];
  }
  if (idx <= N) {
    offs2[idx] = (idx < N) ? offsets[idx] + pp[idx >> 8] : tot;
  }
}

// ---------------- full-K single-barrier MFMA GEMM + fused alpha epilogue ----
// Tile 64x64, K=256 fully staged. B staged first, then A; split drain:
// vmcnt(8) [own B done, in-order retire] -> s_barrier [all B visible] ->
// vmcnt(0) [own A done; A rows are read only by the staging wave].
// LDS element (i,k): idx = i*256 + (k & ~63) + ((k & 63) ^ ((i&7)<<3));
// linear LDS dest with pre-swizzled global source.
template <int H, int OUT8, int SWZ>
__global__ __launch_bounds__(256) void gemm_fullk(
    const ushort_t* __restrict__ Ain, const ushort_t* __restrict__ Bt,
    void* __restrict__ Cout, const float* __restrict__ avs, const float* __restrict__ avd,
    float* __restrict__ as_out, float* __restrict__ ad_out, int M) {
  constexpr int NT = H * 64;
  __shared__ ushort_t As[64 * 256];
  __shared__ ushort_t Bs[64 * 256];
  const int t = threadIdx.x;
  const int w = t >> 6, l = t & 63;

  int id = blockIdx.x;
  if (SWZ) {  // bijective XCD-chunked swizzle (m204 form)
    const int nwg = gridDim.x;
    const int q = nwg >> 3, rm = nwg & 7;
    int xcd = id & 7, idx = id >> 3;
    id = (xcd < rm ? xcd * (q + 1) : rm * (q + 1) + (xcd - rm) * q) + idx;
  }
  const int mt = (H == 1) ? id : (id >> 2);
  const int head = (H == 1) ? 0 : (id & 3);
  const int m0 = mt * 64;

  // ---- stage: B first (8 loads), then A (8 loads) ----
  {
    const int slot = l & 7;
#pragma unroll
    for (int i = 0; i < 8; ++i) {
      const int r = w * 64 + i * 8 + (l >> 3);  // LDS-row
      const int ir = r >> 2, kb = r & 3;
      const int kc = (slot ^ (ir & 7)) << 3;    // pre-swizzled source k
      const int brow = head * 64 + ir;
      gld_lds16(Bt + (size_t)brow * 256 + kb * 64 + kc,
                &Bs[w * 4096 + i * 512]);
    }
#pragma unroll
    for (int i = 0; i < 8; ++i) {
      const int r = w * 64 + i * 8 + (l >> 3);
      const int ir = r >> 2, kb = r & 3;
      const int kc = (slot ^ (ir & 7)) << 3;
      const int arow = min(m0 + ir, M - 1);
      gld_lds16(Ain + (size_t)arow * 256 + kb * 64 + kc,
                &As[w * 4096 + i * 512]);
    }
  }
  asm volatile("s_waitcnt vmcnt(8)" ::: "memory");  // own B complete
  __builtin_amdgcn_s_barrier();                     // all waves' B visible
  asm volatile("s_waitcnt vmcnt(0)" ::: "memory");  // own A complete
  __builtin_amdgcn_sched_barrier(0);

  // ---- compute: wave w owns tile rows [w*16, w*16+16), all 64 cols ----
  f32x4 acc[4];
#pragma unroll
  for (int j = 0; j < 4; ++j) acc[j] = (f32x4){0.f, 0.f, 0.f, 0.f};

  const int fr = l & 15;
  const int kq = (l >> 4) << 3;
  const int fx = (fr & 7) << 3;
  const ushort_t* Ab = &As[(w * 16 + fr) << 8];
  const ushort_t* Bb = &Bs[fr << 8];
#pragma unroll
  for (int k0 = 0; k0 < 256; k0 += 32) {
    const int kabs = k0 + kq;
    const int base = (kabs & ~63) + ((kabs & 63) ^ fx);
    short8 af = *(const short8*)&Ab[base];
#pragma unroll
    for (int j = 0; j < 4; ++j) {
      short8 bf8 = *(const short8*)&Bb[j * 4096 + base];
      acc[j] = __builtin_amdgcn_mfma_f32_16x16x32_bf16(af, bf8, acc[j], 0, 0, 0);
    }
  }

  // ---- C write ----
  const int rbase = m0 + w * 16 + (l >> 4) * 4;
  const int cb = head * 64 + fr;
#pragma unroll
  for (int j = 0; j < 4; ++j)
#pragma unroll
    for (int r4 = 0; r4 < 4; ++r4) {
      int row = rbase + r4;
      if (row < M) {
        if (OUT8)
          ((uchar_t*)Cout)[(size_t)row * NT + cb + j * 16] = f2fp8(acc[j][r4]);
        else
          ((ushort_t*)Cout)[(size_t)row * NT + cb + j * 16] = f2bf(acc[j][r4]);
      }
    }

  // ---- alpha epilogue ----
  float asw[4], adw[4];
#pragma unroll
  for (int j = 0; j < 4; ++j) {
    asw[j] = avs[head * 64 + fr + j * 16];
    adw[j] = avd[head * 64 + fr + j * 16];
  }
#pragma unroll
  for (int r4 = 0; r4 < 4; ++r4) {
    float s_ = acc[0][r4] * asw[0] + acc[1][r4] * asw[1] +
               acc[2][r4] * asw[2] + acc[3][r4] * asw[3];
    float d_ = acc[0][r4] * adw[0] + acc[1][r4] * adw[1] +
               acc[2][r4] * adw[2] + acc[3][r4] * adw[3];
#pragma unroll
    for (int o = 1; o < 16; o <<= 1) {
      s_ += __shfl_xor(s_, o, 64);
      d_ += __shfl_xor(d_, o, 64);
    }
    if ((l & 15) == 0) {
      int row = rbase + r4;
      if (row < M) {
        as_out[(size_t)row * H + head] = s_;
        ad_out[(size_t)row * H + head] = d_;
      }
    }
  }
}

// ---------------- layer 1 agg (R11): lane-exclusive features ----------------
__global__ __launch_bounds__(256) void agg1_kernel(
    const uchar_t* __restrict__ h1, const int* __restrict__ offsets,
    const int* __restrict__ csr, const float* __restrict__ as1,
    const float* __restrict__ ad1,
    const float* __restrict__ S1, const float* __restrict__ T1,
    ushort_t* __restrict__ out, int N) {
  __shared__ float ldsW[4][64][4];
  const int wv = threadIdx.x >> 6;
  int n = blockIdx.x * 4 + wv;
  int l = threadIdx.x & 63;
  if (n >= N) return;
  const int hh = l >> 4;                 // head of this lane's 4 features
  int off = offsets[n], deg = offsets[n + 1] - off;
  const int* csrp = csr + off;
  const unsigned fb = (unsigned)l << 2;  // feature byte offset within row
  float4 adn = *(const float4*)&ad1[n * 4];
  float ad_h = (hh & 2) ? ((hh & 1) ? adn.w : adn.z) : ((hh & 1) ? adn.y : adn.x);

  f32x2 acc0 = {0.f, 0.f}, acc1 = {0.f, 0.f};
  float den = 0.f;

  for (int base = 0; base < deg; base += 64) {
    int cnt = min(64, deg - base);
    int s = 0;
    float4 w4 = make_float4(0.f, 0.f, 0.f, 0.f);
    if (l < cnt) {
      s = csrp[base + l];  // coalesced
      float4 a4 = *(const float4*)&as1[s * 4];
      w4.x = __expf(leaky02(a4.x + adn.x));
      w4.y = __expf(leaky02(a4.y + adn.y));
      w4.z = __expf(leaky02(a4.z + adn.z));
      w4.w = __expf(leaky02(a4.w + adn.w));
    }
    *(float4*)&ldsW[wv][l][0] = w4;
    for (int j = 0; j < cnt; j += 8) {
#pragma unroll
      for (int i = 0; i < 8; ++i) {
        int e = j + i;  // wave-uniform, <= 63 (padded slots have w=0, s=0)
        unsigned se = (unsigned)__builtin_amdgcn_readlane(s, e);
        float we = ldsW[wv][e][hh];  // 4-addr broadcast read
        unsigned q = *(const unsigned*)(h1 + (size_t)((se << 8) + fb));
        f32x2 lo = __builtin_amdgcn_cvt_pk_f32_fp8(q, false);
        f32x2 hi = __builtin_amdgcn_cvt_pk_f32_fp8(q, true);
        f32x2 w2 = {we, we};
        acc0 = lo * w2 + acc0;  // v_pk_fma_f32
        acc1 = hi * w2 + acc1;
        den += we;
      }
    }
  }

  // self loop: select head first -> one exp
  float4 asn = *(const float4*)&as1[n * 4];
  float as_h = (hh & 2) ? ((hh & 1) ? asn.w : asn.z) : ((hh & 1) ? asn.y : asn.x);
  float ws = __expf(leaky02(as_h + ad_h));
  {
    unsigned q = *(const unsigned*)(h1 + (size_t)(((unsigned)n << 8) + fb));
    f32x2 lo = __builtin_amdgcn_cvt_pk_f32_fp8(q, false);
    f32x2 hi = __builtin_amdgcn_cvt_pk_f32_fp8(q, true);
    f32x2 w2 = {ws, ws};
    acc0 = lo * w2 + acc0;
    acc1 = hi * w2 + acc1;
  }
  float inv = 1.f / (den + ws + 1e-16f);

  const int c0 = l * 4;
  float4 Sv = *(const float4*)&S1[c0];
  float4 Tv = *(const float4*)&T1[c0];
  float o0 = fmaf(acc0.x, inv * Sv.x, Tv.x);
  float o1 = fmaf(acc0.y, inv * Sv.y, Tv.y);
  float o2 = fmaf(acc1.x, inv * Sv.z, Tv.z);
  float o3 = fmaf(acc1.y, inv * Sv.w, Tv.w);
  ushort4v o4;
  o4[0] = f2bf(elu_fast(o0));
  o4[1] = f2bf(elu_fast(o1));
  o4[2] = f2bf(elu_fast(o2));
  o4[3] = f2bf(elu_fast(o3));
  *(ushort4v*)&out[(size_t)n * 256 + c0] = o4;
}

// ---------------- layer 2 agg: inline weights, 16 edges/iter, fused heads ----------------
__global__ __launch_bounds__(256) void agg2_kernel(
    const ushort_t* __restrict__ h2, const int* __restrict__ offsets,
    const int* __restrict__ csr, const float* __restrict__ as2,
    const float* __restrict__ ad2,
    const float* __restrict__ S2, const float* __restrict__ T2,
    const float* __restrict__ Wr, const float* __restrict__ br,
    const float* __restrict__ Wc, const float* __restrict__ bc,
    float* __restrict__ out_reg, float* __restrict__ out_clf, int N) {
  __shared__ float ldsW[4][64];
  __shared__ int ldsS[4][64];
  const int wv = threadIdx.x >> 6;
  int n = blockIdx.x * 4 + wv;
  int l = threadIdx.x & 63;
  if (n >= N) return;
  const int g = l >> 4, ll = l & 15;
  int off = offsets[n], deg = offsets[n + 1] - off;
  const int* csrp = csr + off;
  const size_t hoff = (size_t)ll * 4;
  float adn = ad2[n];

  float acc[4] = {0, 0, 0, 0};
  float ds = 0.f;

  for (int base = 0; base < deg; base += 64) {
    int cnt = min(64, deg - base);
    int s = 0;
    float wv_ = 0.f;
    if (l < cnt) {
      s = csrp[base + l];
      wv_ = __expf(leaky02(as2[s] + adn));
    }
    ldsS[wv][l] = s;
    ldsW[wv][l] = wv_;
    ds += wv_;
    for (int j = 0; j < cnt; j += 16) {
      int e0 = j + g, e1 = j + 4 + g, e2 = j + 8 + g, e3 = j + 12 + g;  // <= 63
      int s0 = ldsS[wv][e0], s1 = ldsS[wv][e1], s2 = ldsS[wv][e2], s3 = ldsS[wv][e3];
      float w0 = ldsW[wv][e0], w1 = ldsW[wv][e1], w2 = ldsW[wv][e2], w3 = ldsW[wv][e3];
      ushort4v r0 = *(const ushort4v*)&h2[(size_t)s0 * 64 + hoff];
      ushort4v r1 = *(const ushort4v*)&h2[(size_t)s1 * 64 + hoff];
      ushort4v r2 = *(const ushort4v*)&h2[(size_t)s2 * 64 + hoff];
      ushort4v r3 = *(const ushort4v*)&h2[(size_t)s3 * 64 + hoff];
#pragma unroll
      for (int k = 0; k < 4; ++k) acc[k] = fmaf(w0, bf2f(r0[k]), acc[k]);
#pragma unroll
      for (int k = 0; k < 4; ++k) acc[k] = fmaf(w1, bf2f(r1[k]), acc[k]);
#pragma unroll
      for (int k = 0; k < 4; ++k) acc[k] = fmaf(w2, bf2f(r2[k]), acc[k]);
#pragma unroll
      for (int k = 0; k < 4; ++k) acc[k] = fmaf(w3, bf2f(r3[k]), acc[k]);
    }
  }
#pragma unroll
  for (int k = 0; k < 4; ++k) {
    acc[k] += __shfl_xor(acc[k], 16, 64);
    acc[k] += __shfl_xor(acc[k], 32, 64);
  }
  float den = wave_sum(ds);
  float ws = __expf(leaky02(as2[n] + adn));
  ushort4v hn = *(const ushort4v*)&h2[(size_t)n * 64 + hoff];
#pragma unroll
  for (int k = 0; k < 4; ++k) acc[k] = fmaf(ws, bf2f(hn[k]), acc[k]);
  float inv = 1.f / (den + ws + 1e-16f);

  int c0 = ll * 4;
  float4 Sv = *(const float4*)&S2[c0];
  float4 Tv = *(const float4*)&T2[c0];
  float4 wr = *(const float4*)&Wr[c0];
  float4 wc = *(const float4*)&Wc[c0];
  float Sf[4] = {Sv.x, Sv.y, Sv.z, Sv.w};
  float Tf[4] = {Tv.x, Tv.y, Tv.z, Tv.w};
  float wrf[4] = {wr.x, wr.y, wr.z, wr.w};
  float wcf[4] = {wc.x, wc.y, wc.z, wc.w};
  float rs = 0.f, cs = 0.f;
#pragma unroll
  for (int q = 0; q < 4; ++q) {
    float o = fmaf(acc[q], inv * Sf[q], Tf[q]);
    o = elu_fast(o);
    rs = fmaf(o, wrf[q], rs);
    cs = fmaf(o, wcf[q], cs);
  }
#pragma unroll
  for (int o = 1; o < 16; o <<= 1) {
    rs += __shfl_xor(rs, o, 64);
    cs += __shfl_xor(cs, o, 64);
  }
  if (l == 0) {
    out_reg[n] = rs + br[0];
    float z = cs + bc[0];
    out_clf[n] = 1.f / (1.f + __expf(-z));
  }
}

// ---------------- launcher ----------------
extern "C" void kernel_launch(void* const* d_in, const int* in_sizes, int n_in,
                              void* d_out, int out_size, void* d_ws, size_t ws_size,
                              hipStream_t stream) {
  const float* x      = (const float*)d_in[0];
  const int*   ei     = (const int*)d_in[1];
  const float* W1     = (const float*)d_in[2];
  const float* a_src1 = (const float*)d_in[3];
  const float* a_dst1 = (const float*)d_in[4];
  const float* b1     = (const float*)d_in[5];
  const float* bn1w   = (const float*)d_in[6];
  const float* bn1b   = (const float*)d_in[7];
  const float* bn1m   = (const float*)d_in[8];
  const float* bn1v   = (const float*)d_in[9];
  const float* W2     = (const float*)d_in[10];
  const float* a_src2 = (const float*)d_in[11];
  const float* a_dst2 = (const float*)d_in[12];
  const float* b2     = (const float*)d_in[13];
  const float* bn2w   = (const float*)d_in[14];
  const float* bn2b   = (const float*)d_in[15];
  const float* bn2m   = (const float*)d_in[16];
  const float* bn2v   = (const float*)d_in[17];
  const float* Wr     = (const float*)d_in[18];
  const float* br     = (const float*)d_in[19];
  const float* Wc     = (const float*)d_in[20];
  const float* bc     = (const float*)d_in[21];

  const int N = in_sizes[0] / 256;  // 50000
  const int E = in_sizes[1] / 2;    // 400000
  const int* srcv = ei;
  const int* dstv = ei + E;

  char* w = (char*)d_ws;
  auto alloc = [&](size_t bytes) {
    char* p = w;
    w += (bytes + 255) & ~(size_t)255;
    return p;
  };
  const int nb = (N + 255) / 256;  // 196 chunks of 256
  const size_t nbytes_rounded = ((size_t)N * 4 + 255) & ~(size_t)255;
  int* counts    = (int*)alloc((size_t)N * 4);
  int* cursor    = (int*)alloc((size_t)N * 4);  // contiguous with counts
  int* offsets   = (int*)alloc((size_t)N * 4);  // chunk-local scan
  int* offs2     = (int*)alloc((size_t)(N + 1) * 4);  // finalized
  int* partials  = (int*)alloc((size_t)nb * 4);
  int* csr_src   = (int*)alloc((size_t)(E + 64) * 4);  // +64 zero pad
  float* as1     = (float*)alloc((size_t)N * 4 * 4);
  float* ad1     = (float*)alloc((size_t)N * 4 * 4);
  float* as2     = (float*)alloc((size_t)N * 4);
  float* ad2     = (float*)alloc((size_t)N * 4);
  float* S1      = (float*)alloc(256 * 4);
  float* T1      = (float*)alloc(256 * 4);
  float* S2      = (float*)alloc(64 * 4);
  float* T2      = (float*)alloc(64 * 4);
  ushort_t* W1t  = (ushort_t*)alloc((size_t)256 * 256 * 2);
  ushort_t* W2t  = (ushort_t*)alloc((size_t)64 * 256 * 2);
  ushort_t* xb   = (ushort_t*)alloc((size_t)N * 256 * 2);  // bf16 x
  uchar_t* h1b   = (uchar_t*)alloc((size_t)N * 256);       // fp8 e4m3
  ushort_t* h1a  = (ushort_t*)alloc((size_t)N * 256 * 2);  // bf16
  ushort_t* h2b  = (ushort_t*)alloc((size_t)N * 64 * 2);   // bf16

  float* out_reg = (float*)d_out;

  // graph build (4 dispatches) + fused x->bf16 cast
  hipMemsetAsync(counts, 0, nbytes_rounded * 2, stream);  // counts + cursor
  hist_kernel<<<(E + 255) / 256, 256, 0, stream>>>(dstv, counts, E, x, xb, N * 256 / 8);
  scan_chunks_kernel<<<nb, 256, 0, stream>>>(counts, offsets, partials, N, E, csr_src,
                                             W1, W2, W1t, W2t,
                                             b1, bn1w, bn1b, bn1m, bn1v,
                                             b2, bn2w, bn2b, bn2m, bn2v,
                                             S1, T1, S2, T2);
  {
    int items = max(E, N + 1);
    scatter_kernel<<<(items + 255) / 256, 256, 0, stream>>>(srcv, dstv, offsets, partials,
                                                            cursor, csr_src, offs2, E, N, nb);
  }

  const int nwb = (N + 3) / 4;
  const int mtiles = (N + 63) / 64;  // 782

  // layer 1 (gemm1: full-K, XCD-swizzled, fp8 out)
  gemm_fullk<4, 1, 1><<<mtiles * 4, 256, 0, stream>>>(
      xb, W1t, h1b, a_src1, a_dst1, as1, ad1, N);
  agg1_kernel<<<nwb, 256, 0, stream>>>(h1b, offs2, csr_src, as1, ad1, S1, T1, h1a, N);

  // layer 2 (gemm2: full-K, bf16 out)
  gemm_fullk<1, 0, 0><<<mtiles, 256, 0, stream>>>(
      h1a, W2t, h2b, a_src2, a_dst2, as2, ad2, N);
  agg2_kernel<<<nwb, 256, 0, stream>>>(h2b, offs2, csr_src, as2, ad2, S2, T2,
                                       Wr, br, Wc, bc, out_reg, out_reg + N, N);
}

// Round 6
// 253.624 us; speedup vs baseline: 1.0435x; 1.0435x over previous
//
#include <hip/hip_runtime.h>
#include <math.h>

// MultiTaskGNN: 2-layer GAT + BN + ELU + two heads. N=50000, E=400000.
// R16: persistent-B gemm1. W1t (256x256 bf16 = 128KiB) + A-tile (32x256 =
// 16KiB) live in LDS (144KiB, 1 block/CU, 256 blocks x 512 thr). B staged
// ONCE per block; loop grid-strides m-tiles: A loaded fp32 from x into regs
// (prefetch issued after bar2, consumed next iter -> latency hidden under
// MFMA+epilogue), cast in-reg, swizzled ds_write. All 4 heads computed per
// A staging (8 waves = 2 row-halves x 4 heads). x->bf16 cast kernel DELETED
// (hist reverts to pure atomic hist; xb buffer gone). agg1/agg2/gemm2/
// graph-build frozen from R15 (264.6us).

typedef unsigned short ushort_t;
typedef unsigned char uchar_t;
typedef __attribute__((ext_vector_type(8))) unsigned short ushort8;
typedef __attribute__((ext_vector_type(4))) unsigned short ushort4v;
typedef __attribute__((ext_vector_type(8))) short short8;
typedef __attribute__((ext_vector_type(4))) float f32x4;
typedef __attribute__((ext_vector_type(2))) float f32x2;

#define EPS_BN 1e-5f

__device__ __forceinline__ ushort_t f2bf(float f) {  // RNE
  unsigned u = __float_as_uint(f);
  unsigned r = u + 0x7fffu + ((u >> 16) & 1u);
  return (ushort_t)(r >> 16);
}
__device__ __forceinline__ float bf2f(ushort_t h) {
  return __uint_as_float((unsigned)h << 16);
}
__device__ __forceinline__ uchar_t f2fp8(float f) {  // e4m3 via HW cvt (RNE, sat)
  return (uchar_t)(__builtin_amdgcn_cvt_pk_fp8_f32(f, f, 0, false) & 0xff);
}
__device__ __forceinline__ float leaky02(float x) { return x >= 0.f ? x : 0.2f * x; }
__device__ __forceinline__ float elu_fast(float x) {
  return x > 0.f ? x : __expf(x) - 1.f;
}
__device__ __forceinline__ float wave_sum(float v) {
#pragma unroll
  for (int o = 1; o < 64; o <<= 1) v += __shfl_xor(v, o, 64);
  return v;
}
__device__ __forceinline__ int wave_incl_scan(int v, int lane) {
#pragma unroll
  for (int off = 1; off < 64; off <<= 1) {
    int t = __shfl_up(v, off, 64);
    if (lane >= off) v += t;
  }
  return v;
}

__device__ __forceinline__ void gld_lds16(const ushort_t* g, ushort_t* l) {
  __builtin_amdgcn_global_load_lds(
      (const __attribute__((address_space(1))) unsigned int*)g,
      (__attribute__((address_space(3))) unsigned int*)l, 16, 0, 0);
}

// ---------------- hist (pure atomic histogram again) ----------------
__global__ __launch_bounds__(256) void hist_kernel(
    const int* __restrict__ dst, int* __restrict__ counts, int E) {
  int e = blockIdx.x * blockDim.x + threadIdx.x;
  if (e < E) atomicAdd(&counts[dst[e]], 1);
}

// ---------------- scan chunks (256/block) + merged prep work ----------------
__global__ __launch_bounds__(256) void scan_chunks_kernel(
    const int* __restrict__ counts, int* __restrict__ offsets, int* __restrict__ partials,
    int N, int E, int* __restrict__ csr_src,
    const float* __restrict__ W1, const float* __restrict__ W2,
    ushort_t* __restrict__ W1t, ushort_t* __restrict__ W2t,
    const float* __restrict__ b1, const float* __restrict__ bn1w,
    const float* __restrict__ bn1b, const float* __restrict__ bn1m,
    const float* __restrict__ bn1v,
    const float* __restrict__ b2, const float* __restrict__ bn2w,
    const float* __restrict__ bn2b, const float* __restrict__ bn2m,
    const float* __restrict__ bn2v,
    float* __restrict__ S1, float* __restrict__ T1,
    float* __restrict__ S2, float* __restrict__ T2) {
  __shared__ int ws[4];
  const int tid = threadIdx.x, lane = tid & 63, wv = tid >> 6;
  const int i = blockIdx.x * 256 + tid;
  const int gsz = gridDim.x * 256;
  int v = (i < N) ? counts[i] : 0;
  int incl = wave_incl_scan(v, lane);
  if (lane == 63) ws[wv] = incl;
  __syncthreads();
  int wbase = 0;
  for (int k = 0; k < wv; ++k) wbase += ws[k];
  if (i < N) offsets[i] = wbase + incl - v;  // chunk-local exclusive
  if (tid == 255) partials[blockIdx.x] = wbase + incl;

  for (int j = i; j < 256 * 256; j += gsz) {
    int k = j >> 8, n2 = j & 255;
    W1t[n2 * 256 + k] = f2bf(W1[j]);
  }
  for (int j = i; j < 256 * 64; j += gsz) {
    int k = j >> 6, n2 = j & 63;
    W2t[n2 * 256 + k] = f2bf(W2[j]);
  }
  if (i < 256) {
    float s = bn1w[i] * rsqrtf(bn1v[i] + EPS_BN);
    S1[i] = s;
    T1[i] = (b1[i] - bn1m[i]) * s + bn1b[i];
  } else if (i < 320) {
    int j = i - 256;
    float s = bn2w[j] * rsqrtf(bn2v[j] + EPS_BN);
    S2[j] = s;
    T2[j] = (b2[j] - bn2m[j]) * s + bn2b[j];
  } else if (i < 384) {
    csr_src[E + i - 320] = 0;  // zero pad for unclamped tail loads
  }
}

// ---------------- scatter + inline pprefix scan + finalize offsets ----------------
__global__ __launch_bounds__(256) void scatter_kernel(
    const int* __restrict__ src, const int* __restrict__ dst,
    const int* __restrict__ offsets, const int* __restrict__ partials,
    int* __restrict__ cursor, int* __restrict__ csr_src,
    int* __restrict__ offs2, int E, int N, int nb) {
  __shared__ int pp[256];
  __shared__ int ws[4];
  __shared__ int tot;
  const int tid = threadIdx.x, lane = tid & 63, wv = tid >> 6;
  int v = (tid < nb) ? partials[tid] : 0;
  int incl = wave_incl_scan(v, lane);
  if (lane == 63) ws[wv] = incl;
  __syncthreads();
  int wbase = 0;
  for (int k = 0; k < wv; ++k) wbase += ws[k];
  pp[tid] = wbase + incl - v;
  if (tid == 255) tot = wbase + incl;
  __syncthreads();

  int idx = blockIdx.x * 256 + tid;
  if (idx < E) {
    int d = dst[idx];
    int p = atomicAdd(&cursor[d], 1);
    csr_src[offsets[d] + pp[d >> 8] + p] = src[idx];
  }
  if (idx <= N) {
    offs2[idx] = (idx < N) ? offsets[idx] + pp[idx >> 8] : tot;
  }
}

// ---------------- gemm1: persistent-B, fp32 A in-reg cast ----------------
// 256 blocks x 512 threads, 1 block/CU. LDS: Bs = full W1t 256x256 bf16
// (128KiB, staged once), As = 32x256 bf16 (16KiB, restaged per m-tile).
// Swizzle: elem (i,k) at idx = i*256 + (k & ~63) + ((k & 63) ^ ((i&7)<<3)).
// 8 waves = (2 row-halves) x (4 heads). Per tile: cast prefetched fp32 A ->
// bar -> ds_write -> bar -> prefetch next A -> 32 MFMA + C/alpha epilogue.
__global__ __launch_bounds__(512) void gemm1_persist(
    const float* __restrict__ X, const ushort_t* __restrict__ Bt,
    uchar_t* __restrict__ Cout, const float* __restrict__ avs,
    const float* __restrict__ avd,
    float* __restrict__ as_out, float* __restrict__ ad_out, int M, int ntiles) {
  __shared__ ushort_t Bs[256 * 256];
  __shared__ ushort_t As[32 * 256];
  const int t = threadIdx.x;
  const int w = t >> 6, l = t & 63;
  const int wr = w >> 2, wc = w & 3;  // row-half, head

  // ---- stage B once: 8192 slots of 16B over 512 threads ----
#pragma unroll
  for (int it = 0; it < 16; ++it) {
    int s = it * 512 + t;
    int i = s >> 5, sr = s & 31;
    int kb = sr >> 3, sl8 = sr & 7;
    int kc = (sl8 ^ (i & 7)) << 3;
    gld_lds16(Bt + (size_t)i * 256 + kb * 64 + kc, &Bs[s * 8]);
  }

  // ---- A staging geometry: thread -> (row ar, 16-float k-run at k0a) ----
  const int ar = t >> 4, k0a = (t & 15) * 16;
  int wd0, wd1;
  {
    int k = k0a;
    wd0 = ar * 256 + (k & ~63) + ((k & 63) ^ ((ar & 7) << 3));
    k = k0a + 8;
    wd1 = ar * 256 + (k & ~63) + ((k & 63) ^ ((ar & 7) << 3));
  }
  float4 fa0, fa1, fa2, fa3;
  {
    const float* src = X + (size_t)min(blockIdx.x * 32 + ar, M - 1) * 256 + k0a;
    fa0 = *(const float4*)(src);
    fa1 = *(const float4*)(src + 4);
    fa2 = *(const float4*)(src + 8);
    fa3 = *(const float4*)(src + 12);
  }

  const int fr = l & 15;
  const int kq = (l >> 4) << 3;
  const int fx = (fr & 7) << 3;
  const ushort_t* Ab = &As[(wr * 16 + fr) << 8];
  const ushort_t* Bb = &Bs[(wc * 64 + fr) << 8];

  float asw[4], adw[4];
#pragma unroll
  for (int j = 0; j < 4; ++j) {
    asw[j] = avs[wc * 64 + fr + j * 16];
    adw[j] = avd[wc * 64 + fr + j * 16];
  }

  for (int tile = blockIdx.x; tile < ntiles; tile += 256) {
    // cast prefetched fp32 -> bf16 (compiler auto-waits on fa here)
    ushort8 u0, u1;
    u0[0] = f2bf(fa0.x); u0[1] = f2bf(fa0.y); u0[2] = f2bf(fa0.z); u0[3] = f2bf(fa0.w);
    u0[4] = f2bf(fa1.x); u0[5] = f2bf(fa1.y); u0[6] = f2bf(fa1.z); u0[7] = f2bf(fa1.w);
    u1[0] = f2bf(fa2.x); u1[1] = f2bf(fa2.y); u1[2] = f2bf(fa2.z); u1[3] = f2bf(fa2.w);
    u1[4] = f2bf(fa3.x); u1[5] = f2bf(fa3.y); u1[6] = f2bf(fa3.z); u1[7] = f2bf(fa3.w);
    __syncthreads();  // previous tile's MFMA done reading As
    *(ushort8*)&As[wd0] = u0;
    *(ushort8*)&As[wd1] = u1;
    __syncthreads();  // As visible (and Bs on first iter via vmcnt drain)

    // prefetch next tile's A AFTER the barrier -> stays in flight over MFMA
    {
      int nt_ = tile + 256;
      if (nt_ < ntiles) {
        const float* src = X + (size_t)min(nt_ * 32 + ar, M - 1) * 256 + k0a;
        fa0 = *(const float4*)(src);
        fa1 = *(const float4*)(src + 4);
        fa2 = *(const float4*)(src + 8);
        fa3 = *(const float4*)(src + 12);
      }
    }

    // ---- compute: 8 K-steps x 4 col-frags ----
    f32x4 acc[4];
#pragma unroll
    for (int j = 0; j < 4; ++j) acc[j] = (f32x4){0.f, 0.f, 0.f, 0.f};
#pragma unroll
    for (int k0 = 0; k0 < 256; k0 += 32) {
      const int kabs = k0 + kq;
      const int base = (kabs & ~63) + ((kabs & 63) ^ fx);
      short8 af = *(const short8*)&Ab[base];
#pragma unroll
      for (int j = 0; j < 4; ++j) {
        short8 bf8 = *(const short8*)&Bb[j * 4096 + base];
        acc[j] = __builtin_amdgcn_mfma_f32_16x16x32_bf16(af, bf8, acc[j], 0, 0, 0);
      }
    }

    // ---- C write (fp8) ----
    const int rbase = tile * 32 + wr * 16 + (l >> 4) * 4;
#pragma unroll
    for (int j = 0; j < 4; ++j)
#pragma unroll
      for (int r4 = 0; r4 < 4; ++r4) {
        int row = rbase + r4;
        if (row < M)
          Cout[(size_t)row * 256 + wc * 64 + fr + j * 16] = f2fp8(acc[j][r4]);
      }

    // ---- alpha epilogue ----
#pragma unroll
    for (int r4 = 0; r4 < 4; ++r4) {
      float s_ = acc[0][r4] * asw[0] + acc[1][r4] * asw[1] +
                 acc[2][r4] * asw[2] + acc[3][r4] * asw[3];
      float d_ = acc[0][r4] * adw[0] + acc[1][r4] * adw[1] +
                 acc[2][r4] * adw[2] + acc[3][r4] * adw[3];
#pragma unroll
      for (int o = 1; o < 16; o <<= 1) {
        s_ += __shfl_xor(s_, o, 64);
        d_ += __shfl_xor(d_, o, 64);
      }
      if ((l & 15) == 0) {
        int row = rbase + r4;
        if (row < M) {
          as_out[(size_t)row * 4 + wc] = s_;
          ad_out[(size_t)row * 4 + wc] = d_;
        }
      }
    }
  }
}

// ---------------- gemm2: full-K single-barrier (R15 form, H=1) ----------------
__global__ __launch_bounds__(256) void gemm2_fullk(
    const ushort_t* __restrict__ Ain, const ushort_t* __restrict__ Bt,
    ushort_t* __restrict__ Cout, const float* __restrict__ avs,
    const float* __restrict__ avd,
    float* __restrict__ as_out, float* __restrict__ ad_out, int M) {
  __shared__ ushort_t As[64 * 256];
  __shared__ ushort_t Bs[64 * 256];
  const int t = threadIdx.x;
  const int w = t >> 6, l = t & 63;
  const int m0 = blockIdx.x * 64;

  {
    const int slot = l & 7;
#pragma unroll
    for (int i = 0; i < 8; ++i) {
      const int r = w * 64 + i * 8 + (l >> 3);
      const int ir = r >> 2, kb = r & 3;
      const int kc = (slot ^ (ir & 7)) << 3;
      gld_lds16(Bt + (size_t)ir * 256 + kb * 64 + kc, &Bs[w * 4096 + i * 512]);
    }
#pragma unroll
    for (int i = 0; i < 8; ++i) {
      const int r = w * 64 + i * 8 + (l >> 3);
      const int ir = r >> 2, kb = r & 3;
      const int kc = (slot ^ (ir & 7)) << 3;
      const int arow = min(m0 + ir, M - 1);
      gld_lds16(Ain + (size_t)arow * 256 + kb * 64 + kc, &As[w * 4096 + i * 512]);
    }
  }
  asm volatile("s_waitcnt vmcnt(8)" ::: "memory");  // own B complete
  __builtin_amdgcn_s_barrier();                     // all waves' B visible
  asm volatile("s_waitcnt vmcnt(0)" ::: "memory");  // own A complete (self-read)
  __builtin_amdgcn_sched_barrier(0);

  f32x4 acc[4];
#pragma unroll
  for (int j = 0; j < 4; ++j) acc[j] = (f32x4){0.f, 0.f, 0.f, 0.f};

  const int fr = l & 15;
  const int kq = (l >> 4) << 3;
  const int fx = (fr & 7) << 3;
  const ushort_t* Ab = &As[(w * 16 + fr) << 8];
  const ushort_t* Bb = &Bs[fr << 8];
#pragma unroll
  for (int k0 = 0; k0 < 256; k0 += 32) {
    const int kabs = k0 + kq;
    const int base = (kabs & ~63) + ((kabs & 63) ^ fx);
    short8 af = *(const short8*)&Ab[base];
#pragma unroll
    for (int j = 0; j < 4; ++j) {
      short8 bf8 = *(const short8*)&Bb[j * 4096 + base];
      acc[j] = __builtin_amdgcn_mfma_f32_16x16x32_bf16(af, bf8, acc[j], 0, 0, 0);
    }
  }

  const int rbase = m0 + w * 16 + (l >> 4) * 4;
#pragma unroll
  for (int j = 0; j < 4; ++j)
#pragma unroll
    for (int r4 = 0; r4 < 4; ++r4) {
      int row = rbase + r4;
      if (row < M)
        Cout[(size_t)row * 64 + fr + j * 16] = f2bf(acc[j][r4]);
    }

  float asw[4], adw[4];
#pragma unroll
  for (int j = 0; j < 4; ++j) {
    asw[j] = avs[fr + j * 16];
    adw[j] = avd[fr + j * 16];
  }
#pragma unroll
  for (int r4 = 0; r4 < 4; ++r4) {
    float s_ = acc[0][r4] * asw[0] + acc[1][r4] * asw[1] +
               acc[2][r4] * asw[2] + acc[3][r4] * asw[3];
    float d_ = acc[0][r4] * adw[0] + acc[1][r4] * adw[1] +
               acc[2][r4] * adw[2] + acc[3][r4] * adw[3];
#pragma unroll
    for (int o = 1; o < 16; o <<= 1) {
      s_ += __shfl_xor(s_, o, 64);
      d_ += __shfl_xor(d_, o, 64);
    }
    if ((l & 15) == 0) {
      int row = rbase + r4;
      if (row < M) {
        as_out[row] = s_;
        ad_out[row] = d_;
      }
    }
  }
}

// ---------------- layer 1 agg (R11): lane-exclusive features ----------------
__global__ __launch_bounds__(256) void agg1_kernel(
    const uchar_t* __restrict__ h1, const int* __restrict__ offsets,
    const int* __restrict__ csr, const float* __restrict__ as1,
    const float* __restrict__ ad1,
    const float* __restrict__ S1, const float* __restrict__ T1,
    ushort_t* __restrict__ out, int N) {
  __shared__ float ldsW[4][64][4];
  const int wv = threadIdx.x >> 6;
  int n = blockIdx.x * 4 + wv;
  int l = threadIdx.x & 63;
  if (n >= N) return;
  const int hh = l >> 4;                 // head of this lane's 4 features
  int off = offsets[n], deg = offsets[n + 1] - off;
  const int* csrp = csr + off;
  const unsigned fb = (unsigned)l << 2;  // feature byte offset within row
  float4 adn = *(const float4*)&ad1[n * 4];
  float ad_h = (hh & 2) ? ((hh & 1) ? adn.w : adn.z) : ((hh & 1) ? adn.y : adn.x);

  f32x2 acc0 = {0.f, 0.f}, acc1 = {0.f, 0.f};
  float den = 0.f;

  for (int base = 0; base < deg; base += 64) {
    int cnt = min(64, deg - base);
    int s = 0;
    float4 w4 = make_float4(0.f, 0.f, 0.f, 0.f);
    if (l < cnt) {
      s = csrp[base + l];  // coalesced
      float4 a4 = *(const float4*)&as1[s * 4];
      w4.x = __expf(leaky02(a4.x + adn.x));
      w4.y = __expf(leaky02(a4.y + adn.y));
      w4.z = __expf(leaky02(a4.z + adn.z));
      w4.w = __expf(leaky02(a4.w + adn.w));
    }
    *(float4*)&ldsW[wv][l][0] = w4;
    for (int j = 0; j < cnt; j += 8) {
#pragma unroll
      for (int i = 0; i < 8; ++i) {
        int e = j + i;  // wave-uniform, <= 63 (padded slots have w=0, s=0)
        unsigned se = (unsigned)__builtin_amdgcn_readlane(s, e);
        float we = ldsW[wv][e][hh];  // 4-addr broadcast read
        unsigned q = *(const unsigned*)(h1 + (size_t)((se << 8) + fb));
        f32x2 lo = __builtin_amdgcn_cvt_pk_f32_fp8(q, false);
        f32x2 hi = __builtin_amdgcn_cvt_pk_f32_fp8(q, true);
        f32x2 w2 = {we, we};
        acc0 = lo * w2 + acc0;  // v_pk_fma_f32
        acc1 = hi * w2 + acc1;
        den += we;
      }
    }
  }

  // self loop: select head first -> one exp
  float4 asn = *(const float4*)&as1[n * 4];
  float as_h = (hh & 2) ? ((hh & 1) ? asn.w : asn.z) : ((hh & 1) ? asn.y : asn.x);
  float ws = __expf(leaky02(as_h + ad_h));
  {
    unsigned q = *(const unsigned*)(h1 + (size_t)(((unsigned)n << 8) + fb));
    f32x2 lo = __builtin_amdgcn_cvt_pk_f32_fp8(q, false);
    f32x2 hi = __builtin_amdgcn_cvt_pk_f32_fp8(q, true);
    f32x2 w2 = {ws, ws};
    acc0 = lo * w2 + acc0;
    acc1 = hi * w2 + acc1;
  }
  float inv = 1.f / (den + ws + 1e-16f);

  const int c0 = l * 4;
  float4 Sv = *(const float4*)&S1[c0];
  float4 Tv = *(const float4*)&T1[c0];
  float o0 = fmaf(acc0.x, inv * Sv.x, Tv.x);
  float o1 = fmaf(acc0.y, inv * Sv.y, Tv.y);
  float o2 = fmaf(acc1.x, inv * Sv.z, Tv.z);
  float o3 = fmaf(acc1.y, inv * Sv.w, Tv.w);
  ushort4v o4;
  o4[0] = f2bf(elu_fast(o0));
  o4[1] = f2bf(elu_fast(o1));
  o4[2] = f2bf(elu_fast(o2));
  o4[3] = f2bf(elu_fast(o3));
  *(ushort4v*)&out[(size_t)n * 256 + c0] = o4;
}

// ---------------- layer 2 agg: inline weights, 16 edges/iter, fused heads ----------------
__global__ __launch_bounds__(256) void agg2_kernel(
    const ushort_t* __restrict__ h2, const int* __restrict__ offsets,
    const int* __restrict__ csr, const float* __restrict__ as2,
    const float* __restrict__ ad2,
    const float* __restrict__ S2, const float* __restrict__ T2,
    const float* __restrict__ Wr, const float* __restrict__ br,
    const float* __restrict__ Wc, const float* __restrict__ bc,
    float* __restrict__ out_reg, float* __restrict__ out_clf, int N) {
  __shared__ float ldsW[4][64];
  __shared__ int ldsS[4][64];
  const int wv = threadIdx.x >> 6;
  int n = blockIdx.x * 4 + wv;
  int l = threadIdx.x & 63;
  if (n >= N) return;
  const int g = l >> 4, ll = l & 15;
  int off = offsets[n], deg = offsets[n + 1] - off;
  const int* csrp = csr + off;
  const size_t hoff = (size_t)ll * 4;
  float adn = ad2[n];

  float acc[4] = {0, 0, 0, 0};
  float ds = 0.f;

  for (int base = 0; base < deg; base += 64) {
    int cnt = min(64, deg - base);
    int s = 0;
    float wv_ = 0.f;
    if (l < cnt) {
      s = csrp[base + l];
      wv_ = __expf(leaky02(as2[s] + adn));
    }
    ldsS[wv][l] = s;
    ldsW[wv][l] = wv_;
    ds += wv_;
    for (int j = 0; j < cnt; j += 16) {
      int e0 = j + g, e1 = j + 4 + g, e2 = j + 8 + g, e3 = j + 12 + g;  // <= 63
      int s0 = ldsS[wv][e0], s1 = ldsS[wv][e1], s2 = ldsS[wv][e2], s3 = ldsS[wv][e3];
      float w0 = ldsW[wv][e0], w1 = ldsW[wv][e1], w2 = ldsW[wv][e2], w3 = ldsW[wv][e3];
      ushort4v r0 = *(const ushort4v*)&h2[(size_t)s0 * 64 + hoff];
      ushort4v r1 = *(const ushort4v*)&h2[(size_t)s1 * 64 + hoff];
      ushort4v r2 = *(const ushort4v*)&h2[(size_t)s2 * 64 + hoff];
      ushort4v r3 = *(const ushort4v*)&h2[(size_t)s3 * 64 + hoff];
#pragma unroll
      for (int k = 0; k < 4; ++k) acc[k] = fmaf(w0, bf2f(r0[k]), acc[k]);
#pragma unroll
      for (int k = 0; k < 4; ++k) acc[k] = fmaf(w1, bf2f(r1[k]), acc[k]);
#pragma unroll
      for (int k = 0; k < 4; ++k) acc[k] = fmaf(w2, bf2f(r2[k]), acc[k]);
#pragma unroll
      for (int k = 0; k < 4; ++k) acc[k] = fmaf(w3, bf2f(r3[k]), acc[k]);
    }
  }
#pragma unroll
  for (int k = 0; k < 4; ++k) {
    acc[k] += __shfl_xor(acc[k], 16, 64);
    acc[k] += __shfl_xor(acc[k], 32, 64);
  }
  float den = wave_sum(ds);
  float ws = __expf(leaky02(as2[n] + adn));
  ushort4v hn = *(const ushort4v*)&h2[(size_t)n * 64 + hoff];
#pragma unroll
  for (int k = 0; k < 4; ++k) acc[k] = fmaf(ws, bf2f(hn[k]), acc[k]);
  float inv = 1.f / (den + ws + 1e-16f);

  int c0 = ll * 4;
  float4 Sv = *(const float4*)&S2[c0];
  float4 Tv = *(const float4*)&T2[c0];
  float4 wr = *(const float4*)&Wr[c0];
  float4 wc = *(const float4*)&Wc[c0];
  float Sf[4] = {Sv.x, Sv.y, Sv.z, Sv.w};
  float Tf[4] = {Tv.x, Tv.y, Tv.z, Tv.w};
  float wrf[4] = {wr.x, wr.y, wr.z, wr.w};
  float wcf[4] = {wc.x, wc.y, wc.z, wc.w};
  float rs = 0.f, cs = 0.f;
#pragma unroll
  for (int q = 0; q < 4; ++q) {
    float o = fmaf(acc[q], inv * Sf[q], Tf[q]);
    o = elu_fast(o);
    rs = fmaf(o, wrf[q], rs);
    cs = fmaf(o, wcf[q], cs);
  }
#pragma unroll
  for (int o = 1; o < 16; o <<= 1) {
    rs += __shfl_xor(rs, o, 64);
    cs += __shfl_xor(cs, o, 64);
  }
  if (l == 0) {
    out_reg[n] = rs + br[0];
    float z = cs + bc[0];
    out_clf[n] = 1.f / (1.f + __expf(-z));
  }
}

// ---------------- launcher ----------------
extern "C" void kernel_launch(void* const* d_in, const int* in_sizes, int n_in,
                              void* d_out, int out_size, void* d_ws, size_t ws_size,
                              hipStream_t stream) {
  const float* x      = (const float*)d_in[0];
  const int*   ei     = (const int*)d_in[1];
  const float* W1     = (const float*)d_in[2];
  const float* a_src1 = (const float*)d_in[3];
  const float* a_dst1 = (const float*)d_in[4];
  const float* b1     = (const float*)d_in[5];
  const float* bn1w   = (const float*)d_in[6];
  const float* bn1b   = (const float*)d_in[7];
  const float* bn1m   = (const float*)d_in[8];
  const float* bn1v   = (const float*)d_in[9];
  const float* W2     = (const float*)d_in[10];
  const float* a_src2 = (const float*)d_in[11];
  const float* a_dst2 = (const float*)d_in[12];
  const float* b2     = (const float*)d_in[13];
  const float* bn2w   = (const float*)d_in[14];
  const float* bn2b   = (const float*)d_in[15];
  const float* bn2m   = (const float*)d_in[16];
  const float* bn2v   = (const float*)d_in[17];
  const float* Wr     = (const float*)d_in[18];
  const float* br     = (const float*)d_in[19];
  const float* Wc     = (const float*)d_in[20];
  const float* bc     = (const float*)d_in[21];

  const int N = in_sizes[0] / 256;  // 50000
  const int E = in_sizes[1] / 2;    // 400000
  const int* srcv = ei;
  const int* dstv = ei + E;

  char* w = (char*)d_ws;
  auto alloc = [&](size_t bytes) {
    char* p = w;
    w += (bytes + 255) & ~(size_t)255;
    return p;
  };
  const int nb = (N + 255) / 256;  // 196 chunks of 256
  const size_t nbytes_rounded = ((size_t)N * 4 + 255) & ~(size_t)255;
  int* counts    = (int*)alloc((size_t)N * 4);
  int* cursor    = (int*)alloc((size_t)N * 4);  // contiguous with counts
  int* offsets   = (int*)alloc((size_t)N * 4);  // chunk-local scan
  int* offs2     = (int*)alloc((size_t)(N + 1) * 4);  // finalized
  int* partials  = (int*)alloc((size_t)nb * 4);
  int* csr_src   = (int*)alloc((size_t)(E + 64) * 4);  // +64 zero pad
  float* as1     = (float*)alloc((size_t)N * 4 * 4);
  float* ad1     = (float*)alloc((size_t)N * 4 * 4);
  float* as2     = (float*)alloc((size_t)N * 4);
  float* ad2     = (float*)alloc((size_t)N * 4);
  float* S1      = (float*)alloc(256 * 4);
  float* T1      = (float*)alloc(256 * 4);
  float* S2      = (float*)alloc(64 * 4);
  float* T2      = (float*)alloc(64 * 4);
  ushort_t* W1t  = (ushort_t*)alloc((size_t)256 * 256 * 2);
  ushort_t* W2t  = (ushort_t*)alloc((size_t)64 * 256 * 2);
  uchar_t* h1b   = (uchar_t*)alloc((size_t)N * 256);       // fp8 e4m3
  ushort_t* h1a  = (ushort_t*)alloc((size_t)N * 256 * 2);  // bf16
  ushort_t* h2b  = (ushort_t*)alloc((size_t)N * 64 * 2);   // bf16

  float* out_reg = (float*)d_out;

  // graph build (4 dispatches)
  hipMemsetAsync(counts, 0, nbytes_rounded * 2, stream);  // counts + cursor
  hist_kernel<<<(E + 255) / 256, 256, 0, stream>>>(dstv, counts, E);
  scan_chunks_kernel<<<nb, 256, 0, stream>>>(counts, offsets, partials, N, E, csr_src,
                                             W1, W2, W1t, W2t,
                                             b1, bn1w, bn1b, bn1m, bn1v,
                                             b2, bn2w, bn2b, bn2m, bn2v,
                                             S1, T1, S2, T2);
  {
    int items = max(E, N + 1);
    scatter_kernel<<<(items + 255) / 256, 256, 0, stream>>>(srcv, dstv, offsets, partials,
                                                            cursor, csr_src, offs2, E, N, nb);
  }

  const int nwb = (N + 3) / 4;
  const int ntiles1 = (N + 31) / 32;   // 1563
  const int mtiles2 = (N + 63) / 64;   // 782

  // layer 1 (gemm1: persistent-B, fp32 A direct, fp8 out)
  gemm1_persist<<<256, 512, 0, stream>>>(
      x, W1t, h1b, a_src1, a_dst1, as1, ad1, N, ntiles1);
  agg1_kernel<<<nwb, 256, 0, stream>>>(h1b, offs2, csr_src, as1, ad1, S1, T1, h1a, N);

  // layer 2 (gemm2: full-K, bf16 out)
  gemm2_fullk<<<mtiles2, 256, 0, stream>>>(
      h1a, W2t, h2b, a_src2, a_dst2, as2, ad2, N);
  agg2_kernel<<<nwb, 256, 0, stream>>>(h2b, offs2, csr_src, as2, ad2, S2, T2,
                                       Wr, br, Wc, bc, out_reg, out_reg + N, N);
}

// Round 7
// 242.111 us; speedup vs baseline: 1.0931x; 1.0476x over previous
//
#include <hip/hip_runtime.h>
#include <math.h>

// MultiTaskGNN: 2-layer GAT + BN + ELU + two heads. N=50000, E=400000.
// R17: agg2 rewritten lane-exclusive, 2 nodes/wave. Each half-wave owns one
// node; lane owns dword l&31 of the 128B row (full row = 1 coalesced load
// per edge per half). Per edge: 1 ds_read_b64 (s,w packed float2), 2 FMA,
// per-lane den. acc/den complete per-lane -> epilogue fold cascades deleted
// (was 8 shfl acc-fold + 6-shfl wave_sum). Wave count halved (6250 blocks).
// Everything else frozen from R16 (253.6us; est agg1~40, agg2~40-55).

typedef unsigned short ushort_t;
typedef unsigned char uchar_t;
typedef __attribute__((ext_vector_type(8))) unsigned short ushort8;
typedef __attribute__((ext_vector_type(4))) unsigned short ushort4v;
typedef __attribute__((ext_vector_type(8))) short short8;
typedef __attribute__((ext_vector_type(4))) float f32x4;
typedef __attribute__((ext_vector_type(2))) float f32x2;

#define EPS_BN 1e-5f

__device__ __forceinline__ ushort_t f2bf(float f) {  // RNE
  unsigned u = __float_as_uint(f);
  unsigned r = u + 0x7fffu + ((u >> 16) & 1u);
  return (ushort_t)(r >> 16);
}
__device__ __forceinline__ float bf2f(ushort_t h) {
  return __uint_as_float((unsigned)h << 16);
}
__device__ __forceinline__ uchar_t f2fp8(float f) {  // e4m3 via HW cvt (RNE, sat)
  return (uchar_t)(__builtin_amdgcn_cvt_pk_fp8_f32(f, f, 0, false) & 0xff);
}
__device__ __forceinline__ float leaky02(float x) { return x >= 0.f ? x : 0.2f * x; }
__device__ __forceinline__ float elu_fast(float x) {
  return x > 0.f ? x : __expf(x) - 1.f;
}
__device__ __forceinline__ float wave_sum(float v) {
#pragma unroll
  for (int o = 1; o < 64; o <<= 1) v += __shfl_xor(v, o, 64);
  return v;
}
__device__ __forceinline__ int wave_incl_scan(int v, int lane) {
#pragma unroll
  for (int off = 1; off < 64; off <<= 1) {
    int t = __shfl_up(v, off, 64);
    if (lane >= off) v += t;
  }
  return v;
}

__device__ __forceinline__ void gld_lds16(const ushort_t* g, ushort_t* l) {
  __builtin_amdgcn_global_load_lds(
      (const __attribute__((address_space(1))) unsigned int*)g,
      (__attribute__((address_space(3))) unsigned int*)l, 16, 0, 0);
}

// ---------------- hist (pure atomic histogram) ----------------
__global__ __launch_bounds__(256) void hist_kernel(
    const int* __restrict__ dst, int* __restrict__ counts, int E) {
  int e = blockIdx.x * blockDim.x + threadIdx.x;
  if (e < E) atomicAdd(&counts[dst[e]], 1);
}

// ---------------- scan chunks (256/block) + merged prep work ----------------
__global__ __launch_bounds__(256) void scan_chunks_kernel(
    const int* __restrict__ counts, int* __restrict__ offsets, int* __restrict__ partials,
    int N, int E, int* __restrict__ csr_src,
    const float* __restrict__ W1, const float* __restrict__ W2,
    ushort_t* __restrict__ W1t, ushort_t* __restrict__ W2t,
    const float* __restrict__ b1, const float* __restrict__ bn1w,
    const float* __restrict__ bn1b, const float* __restrict__ bn1m,
    const float* __restrict__ bn1v,
    const float* __restrict__ b2, const float* __restrict__ bn2w,
    const float* __restrict__ bn2b, const float* __restrict__ bn2m,
    const float* __restrict__ bn2v,
    float* __restrict__ S1, float* __restrict__ T1,
    float* __restrict__ S2, float* __restrict__ T2) {
  __shared__ int ws[4];
  const int tid = threadIdx.x, lane = tid & 63, wv = tid >> 6;
  const int i = blockIdx.x * 256 + tid;
  const int gsz = gridDim.x * 256;
  int v = (i < N) ? counts[i] : 0;
  int incl = wave_incl_scan(v, lane);
  if (lane == 63) ws[wv] = incl;
  __syncthreads();
  int wbase = 0;
  for (int k = 0; k < wv; ++k) wbase += ws[k];
  if (i < N) offsets[i] = wbase + incl - v;  // chunk-local exclusive
  if (tid == 255) partials[blockIdx.x] = wbase + incl;

  for (int j = i; j < 256 * 256; j += gsz) {
    int k = j >> 8, n2 = j & 255;
    W1t[n2 * 256 + k] = f2bf(W1[j]);
  }
  for (int j = i; j < 256 * 64; j += gsz) {
    int k = j >> 6, n2 = j & 63;
    W2t[n2 * 256 + k] = f2bf(W2[j]);
  }
  if (i < 256) {
    float s = bn1w[i] * rsqrtf(bn1v[i] + EPS_BN);
    S1[i] = s;
    T1[i] = (b1[i] - bn1m[i]) * s + bn1b[i];
  } else if (i < 320) {
    int j = i - 256;
    float s = bn2w[j] * rsqrtf(bn2v[j] + EPS_BN);
    S2[j] = s;
    T2[j] = (b2[j] - bn2m[j]) * s + bn2b[j];
  } else if (i < 384) {
    csr_src[E + i - 320] = 0;  // zero pad for unclamped tail loads
  }
}

// ---------------- scatter + inline pprefix scan + finalize offsets ----------------
__global__ __launch_bounds__(256) void scatter_kernel(
    const int* __restrict__ src, const int* __restrict__ dst,
    const int* __restrict__ offsets, const int* __restrict__ partials,
    int* __restrict__ cursor, int* __restrict__ csr_src,
    int* __restrict__ offs2, int E, int N, int nb) {
  __shared__ int pp[256];
  __shared__ int ws[4];
  __shared__ int tot;
  const int tid = threadIdx.x, lane = tid & 63, wv = tid >> 6;
  int v = (tid < nb) ? partials[tid] : 0;
  int incl = wave_incl_scan(v, lane);
  if (lane == 63) ws[wv] = incl;
  __syncthreads();
  int wbase = 0;
  for (int k = 0; k < wv; ++k) wbase += ws[k];
  pp[tid] = wbase + incl - v;
  if (tid == 255) tot = wbase + incl;
  __syncthreads();

  int idx = blockIdx.x * 256 + tid;
  if (idx < E) {
    int d = dst[idx];
    int p = atomicAdd(&cursor[d], 1);
    csr_src[offsets[d] + pp[d >> 8] + p] = src[idx];
  }
  if (idx <= N) {
    offs2[idx] = (idx < N) ? offsets[idx] + pp[idx >> 8] : tot;
  }
}

// ---------------- gemm1: persistent-B, fp32 A in-reg cast (R16) ----------------
__global__ __launch_bounds__(512) void gemm1_persist(
    const float* __restrict__ X, const ushort_t* __restrict__ Bt,
    uchar_t* __restrict__ Cout, const float* __restrict__ avs,
    const float* __restrict__ avd,
    float* __restrict__ as_out, float* __restrict__ ad_out, int M, int ntiles) {
  __shared__ ushort_t Bs[256 * 256];
  __shared__ ushort_t As[32 * 256];
  const int t = threadIdx.x;
  const int w = t >> 6, l = t & 63;
  const int wr = w >> 2, wc = w & 3;  // row-half, head

  // ---- stage B once: 8192 slots of 16B over 512 threads ----
#pragma unroll
  for (int it = 0; it < 16; ++it) {
    int s = it * 512 + t;
    int i = s >> 5, sr = s & 31;
    int kb = sr >> 3, sl8 = sr & 7;
    int kc = (sl8 ^ (i & 7)) << 3;
    gld_lds16(Bt + (size_t)i * 256 + kb * 64 + kc, &Bs[s * 8]);
  }

  // ---- A staging geometry: thread -> (row ar, 16-float k-run at k0a) ----
  const int ar = t >> 4, k0a = (t & 15) * 16;
  int wd0, wd1;
  {
    int k = k0a;
    wd0 = ar * 256 + (k & ~63) + ((k & 63) ^ ((ar & 7) << 3));
    k = k0a + 8;
    wd1 = ar * 256 + (k & ~63) + ((k & 63) ^ ((ar & 7) << 3));
  }
  float4 fa0, fa1, fa2, fa3;
  {
    const float* src = X + (size_t)min(blockIdx.x * 32 + ar, M - 1) * 256 + k0a;
    fa0 = *(const float4*)(src);
    fa1 = *(const float4*)(src + 4);
    fa2 = *(const float4*)(src + 8);
    fa3 = *(const float4*)(src + 12);
  }

  const int fr = l & 15;
  const int kq = (l >> 4) << 3;
  const int fx = (fr & 7) << 3;
  const ushort_t* Ab = &As[(wr * 16 + fr) << 8];
  const ushort_t* Bb = &Bs[(wc * 64 + fr) << 8];

  float asw[4], adw[4];
#pragma unroll
  for (int j = 0; j < 4; ++j) {
    asw[j] = avs[wc * 64 + fr + j * 16];
    adw[j] = avd[wc * 64 + fr + j * 16];
  }

  for (int tile = blockIdx.x; tile < ntiles; tile += 256) {
    ushort8 u0, u1;
    u0[0] = f2bf(fa0.x); u0[1] = f2bf(fa0.y); u0[2] = f2bf(fa0.z); u0[3] = f2bf(fa0.w);
    u0[4] = f2bf(fa1.x); u0[5] = f2bf(fa1.y); u0[6] = f2bf(fa1.z); u0[7] = f2bf(fa1.w);
    u1[0] = f2bf(fa2.x); u1[1] = f2bf(fa2.y); u1[2] = f2bf(fa2.z); u1[3] = f2bf(fa2.w);
    u1[4] = f2bf(fa3.x); u1[5] = f2bf(fa3.y); u1[6] = f2bf(fa3.z); u1[7] = f2bf(fa3.w);
    __syncthreads();  // previous tile's MFMA done reading As
    *(ushort8*)&As[wd0] = u0;
    *(ushort8*)&As[wd1] = u1;
    __syncthreads();  // As visible (and Bs on first iter via vmcnt drain)

    // prefetch next tile's A AFTER the barrier -> stays in flight over MFMA
    {
      int nt_ = tile + 256;
      if (nt_ < ntiles) {
        const float* src = X + (size_t)min(nt_ * 32 + ar, M - 1) * 256 + k0a;
        fa0 = *(const float4*)(src);
        fa1 = *(const float4*)(src + 4);
        fa2 = *(const float4*)(src + 8);
        fa3 = *(const float4*)(src + 12);
      }
    }

    // ---- compute: 8 K-steps x 4 col-frags ----
    f32x4 acc[4];
#pragma unroll
    for (int j = 0; j < 4; ++j) acc[j] = (f32x4){0.f, 0.f, 0.f, 0.f};
#pragma unroll
    for (int k0 = 0; k0 < 256; k0 += 32) {
      const int kabs = k0 + kq;
      const int base = (kabs & ~63) + ((kabs & 63) ^ fx);
      short8 af = *(const short8*)&Ab[base];
#pragma unroll
      for (int j = 0; j < 4; ++j) {
        short8 bf8 = *(const short8*)&Bb[j * 4096 + base];
        acc[j] = __builtin_amdgcn_mfma_f32_16x16x32_bf16(af, bf8, acc[j], 0, 0, 0);
      }
    }

    // ---- C write (fp8) ----
    const int rbase = tile * 32 + wr * 16 + (l >> 4) * 4;
#pragma unroll
    for (int j = 0; j < 4; ++j)
#pragma unroll
      for (int r4 = 0; r4 < 4; ++r4) {
        int row = rbase + r4;
        if (row < M)
          Cout[(size_t)row * 256 + wc * 64 + fr + j * 16] = f2fp8(acc[j][r4]);
      }

    // ---- alpha epilogue ----
#pragma unroll
    for (int r4 = 0; r4 < 4; ++r4) {
      float s_ = acc[0][r4] * asw[0] + acc[1][r4] * asw[1] +
                 acc[2][r4] * asw[2] + acc[3][r4] * asw[3];
      float d_ = acc[0][r4] * adw[0] + acc[1][r4] * adw[1] +
                 acc[2][r4] * adw[2] + acc[3][r4] * adw[3];
#pragma unroll
      for (int o = 1; o < 16; o <<= 1) {
        s_ += __shfl_xor(s_, o, 64);
        d_ += __shfl_xor(d_, o, 64);
      }
      if ((l & 15) == 0) {
        int row = rbase + r4;
        if (row < M) {
          as_out[(size_t)row * 4 + wc] = s_;
          ad_out[(size_t)row * 4 + wc] = d_;
        }
      }
    }
  }
}

// ---------------- gemm2: full-K single-barrier (R15 form, H=1) ----------------
__global__ __launch_bounds__(256) void gemm2_fullk(
    const ushort_t* __restrict__ Ain, const ushort_t* __restrict__ Bt,
    ushort_t* __restrict__ Cout, const float* __restrict__ avs,
    const float* __restrict__ avd,
    float* __restrict__ as_out, float* __restrict__ ad_out, int M) {
  __shared__ ushort_t As[64 * 256];
  __shared__ ushort_t Bs[64 * 256];
  const int t = threadIdx.x;
  const int w = t >> 6, l = t & 63;
  const int m0 = blockIdx.x * 64;

  {
    const int slot = l & 7;
#pragma unroll
    for (int i = 0; i < 8; ++i) {
      const int r = w * 64 + i * 8 + (l >> 3);
      const int ir = r >> 2, kb = r & 3;
      const int kc = (slot ^ (ir & 7)) << 3;
      gld_lds16(Bt + (size_t)ir * 256 + kb * 64 + kc, &Bs[w * 4096 + i * 512]);
    }
#pragma unroll
    for (int i = 0; i < 8; ++i) {
      const int r = w * 64 + i * 8 + (l >> 3);
      const int ir = r >> 2, kb = r & 3;
      const int kc = (slot ^ (ir & 7)) << 3;
      const int arow = min(m0 + ir, M - 1);
      gld_lds16(Ain + (size_t)arow * 256 + kb * 64 + kc, &As[w * 4096 + i * 512]);
    }
  }
  asm volatile("s_waitcnt vmcnt(8)" ::: "memory");  // own B complete
  __builtin_amdgcn_s_barrier();                     // all waves' B visible
  asm volatile("s_waitcnt vmcnt(0)" ::: "memory");  // own A complete (self-read)
  __builtin_amdgcn_sched_barrier(0);

  f32x4 acc[4];
#pragma unroll
  for (int j = 0; j < 4; ++j) acc[j] = (f32x4){0.f, 0.f, 0.f, 0.f};

  const int fr = l & 15;
  const int kq = (l >> 4) << 3;
  const int fx = (fr & 7) << 3;
  const ushort_t* Ab = &As[(w * 16 + fr) << 8];
  const ushort_t* Bb = &Bs[fr << 8];
#pragma unroll
  for (int k0 = 0; k0 < 256; k0 += 32) {
    const int kabs = k0 + kq;
    const int base = (kabs & ~63) + ((kabs & 63) ^ fx);
    short8 af = *(const short8*)&Ab[base];
#pragma unroll
    for (int j = 0; j < 4; ++j) {
      short8 bf8 = *(const short8*)&Bb[j * 4096 + base];
      acc[j] = __builtin_amdgcn_mfma_f32_16x16x32_bf16(af, bf8, acc[j], 0, 0, 0);
    }
  }

  const int rbase = m0 + w * 16 + (l >> 4) * 4;
#pragma unroll
  for (int j = 0; j < 4; ++j)
#pragma unroll
    for (int r4 = 0; r4 < 4; ++r4) {
      int row = rbase + r4;
      if (row < M)
        Cout[(size_t)row * 64 + fr + j * 16] = f2bf(acc[j][r4]);
    }

  float asw[4], adw[4];
#pragma unroll
  for (int j = 0; j < 4; ++j) {
    asw[j] = avs[fr + j * 16];
    adw[j] = avd[fr + j * 16];
  }
#pragma unroll
  for (int r4 = 0; r4 < 4; ++r4) {
    float s_ = acc[0][r4] * asw[0] + acc[1][r4] * asw[1] +
               acc[2][r4] * asw[2] + acc[3][r4] * asw[3];
    float d_ = acc[0][r4] * adw[0] + acc[1][r4] * adw[1] +
               acc[2][r4] * adw[2] + acc[3][r4] * adw[3];
#pragma unroll
    for (int o = 1; o < 16; o <<= 1) {
      s_ += __shfl_xor(s_, o, 64);
      d_ += __shfl_xor(d_, o, 64);
    }
    if ((l & 15) == 0) {
      int row = rbase + r4;
      if (row < M) {
        as_out[row] = s_;
        ad_out[row] = d_;
      }
    }
  }
}

// ---------------- layer 1 agg (R11): lane-exclusive features ----------------
__global__ __launch_bounds__(256) void agg1_kernel(
    const uchar_t* __restrict__ h1, const int* __restrict__ offsets,
    const int* __restrict__ csr, const float* __restrict__ as1,
    const float* __restrict__ ad1,
    const float* __restrict__ S1, const float* __restrict__ T1,
    ushort_t* __restrict__ out, int N) {
  __shared__ float ldsW[4][64][4];
  const int wv = threadIdx.x >> 6;
  int n = blockIdx.x * 4 + wv;
  int l = threadIdx.x & 63;
  if (n >= N) return;
  const int hh = l >> 4;                 // head of this lane's 4 features
  int off = offsets[n], deg = offsets[n + 1] - off;
  const int* csrp = csr + off;
  const unsigned fb = (unsigned)l << 2;  // feature byte offset within row
  float4 adn = *(const float4*)&ad1[n * 4];
  float ad_h = (hh & 2) ? ((hh & 1) ? adn.w : adn.z) : ((hh & 1) ? adn.y : adn.x);

  f32x2 acc0 = {0.f, 0.f}, acc1 = {0.f, 0.f};
  float den = 0.f;

  for (int base = 0; base < deg; base += 64) {
    int cnt = min(64, deg - base);
    int s = 0;
    float4 w4 = make_float4(0.f, 0.f, 0.f, 0.f);
    if (l < cnt) {
      s = csrp[base + l];  // coalesced
      float4 a4 = *(const float4*)&as1[s * 4];
      w4.x = __expf(leaky02(a4.x + adn.x));
      w4.y = __expf(leaky02(a4.y + adn.y));
      w4.z = __expf(leaky02(a4.z + adn.z));
      w4.w = __expf(leaky02(a4.w + adn.w));
    }
    *(float4*)&ldsW[wv][l][0] = w4;
    for (int j = 0; j < cnt; j += 8) {
#pragma unroll
      for (int i = 0; i < 8; ++i) {
        int e = j + i;  // wave-uniform, <= 63 (padded slots have w=0, s=0)
        unsigned se = (unsigned)__builtin_amdgcn_readlane(s, e);
        float we = ldsW[wv][e][hh];  // 4-addr broadcast read
        unsigned q = *(const unsigned*)(h1 + (size_t)((se << 8) + fb));
        f32x2 lo = __builtin_amdgcn_cvt_pk_f32_fp8(q, false);
        f32x2 hi = __builtin_amdgcn_cvt_pk_f32_fp8(q, true);
        f32x2 w2 = {we, we};
        acc0 = lo * w2 + acc0;  // v_pk_fma_f32
        acc1 = hi * w2 + acc1;
        den += we;
      }
    }
  }

  // self loop: select head first -> one exp
  float4 asn = *(const float4*)&as1[n * 4];
  float as_h = (hh & 2) ? ((hh & 1) ? asn.w : asn.z) : ((hh & 1) ? asn.y : asn.x);
  float ws = __expf(leaky02(as_h + ad_h));
  {
    unsigned q = *(const unsigned*)(h1 + (size_t)(((unsigned)n << 8) + fb));
    f32x2 lo = __builtin_amdgcn_cvt_pk_f32_fp8(q, false);
    f32x2 hi = __builtin_amdgcn_cvt_pk_f32_fp8(q, true);
    f32x2 w2 = {ws, ws};
    acc0 = lo * w2 + acc0;
    acc1 = hi * w2 + acc1;
  }
  float inv = 1.f / (den + ws + 1e-16f);

  const int c0 = l * 4;
  float4 Sv = *(const float4*)&S1[c0];
  float4 Tv = *(const float4*)&T1[c0];
  float o0 = fmaf(acc0.x, inv * Sv.x, Tv.x);
  float o1 = fmaf(acc0.y, inv * Sv.y, Tv.y);
  float o2 = fmaf(acc1.x, inv * Sv.z, Tv.z);
  float o3 = fmaf(acc1.y, inv * Sv.w, Tv.w);
  ushort4v o4;
  o4[0] = f2bf(elu_fast(o0));
  o4[1] = f2bf(elu_fast(o1));
  o4[2] = f2bf(elu_fast(o2));
  o4[3] = f2bf(elu_fast(o3));
  *(ushort4v*)&out[(size_t)n * 256 + c0] = o4;
}

// ---------------- layer 2 agg (R17): lane-exclusive, 2 nodes/wave ----------------
// Half-wave h = l>>5 owns node n = blk*8 + wv*2 + h; lane owns dword q = l&31
// of the 128B row (32 lanes x 4B = full row -> 1 coalesced load per edge per
// half). Per edge: 1 ds_read_b64 (s,w packed), 2 bf16 unpack + 2 FMA, per-lane
// den. acc/den complete per lane -> no cross-lane folds; only the final
// 2-feature head reduce (5 shfl within the half).
__global__ __launch_bounds__(256) void agg2_kernel(
    const ushort_t* __restrict__ h2, const int* __restrict__ offsets,
    const int* __restrict__ csr, const float* __restrict__ as2,
    const float* __restrict__ ad2,
    const float* __restrict__ S2, const float* __restrict__ T2,
    const float* __restrict__ Wr, const float* __restrict__ br,
    const float* __restrict__ Wc, const float* __restrict__ bc,
    float* __restrict__ out_reg, float* __restrict__ out_clf, int N) {
  __shared__ float2 ldsSW[4][64];  // per wave: 32 slots per half: (s_bits, w)
  const int wv = threadIdx.x >> 6;
  const int l = threadIdx.x & 63;
  const int h = l >> 5, q = l & 31;
  int n = blockIdx.x * 8 + wv * 2 + h;
  const bool valid = (n < N);
  if (!valid) n = N - 1;  // clamp for safe reads; writes guarded
  const int off = offsets[n], deg = offsets[n + 1] - off;
  const int* csrp = csr + off;
  const float adn = ad2[n];
  const int degw = max(deg, __shfl_xor(deg, 32, 64));  // wave-uniform bound

  f32x2 acc = {0.f, 0.f};
  float den = 0.f;
  const int hb = h << 5;

  for (int base = 0; base < degw; base += 32) {
    // stage this half's next 32 edges: s + weight packed into one 8B slot
    int s = 0;
    float w_ = 0.f;
    int idx = base + q;
    if (idx < deg) {
      s = csrp[idx];  // coalesced per half
      w_ = __expf(leaky02(as2[s] + adn));
    }
    float2 sw;
    sw.x = __int_as_float(s);
    sw.y = w_;
    ldsSW[wv][l] = sw;
    int cntw = min(32, degw - base);
    for (int j = 0; j < cntw; j += 8) {
#pragma unroll
      for (int i = 0; i < 8; ++i) {
        int e = j + i;  // <= 31; padded slots have w=0, s=0
        float2 t = ldsSW[wv][hb + e];  // 1 ds_read_b64, broadcast per half
        int se = __float_as_int(t.x);
        float we = t.y;
        unsigned d = *(const unsigned*)&h2[(size_t)se * 64 + (q << 1)];
        acc.x = fmaf(we, bf2f((ushort_t)d), acc.x);
        acc.y = fmaf(we, bf2f((ushort_t)(d >> 16)), acc.y);
        den += we;
      }
    }
  }

  // self loop
  float ws = __expf(leaky02(as2[n] + adn));
  {
    unsigned d = *(const unsigned*)&h2[(size_t)n * 64 + (q << 1)];
    acc.x = fmaf(ws, bf2f((ushort_t)d), acc.x);
    acc.y = fmaf(ws, bf2f((ushort_t)(d >> 16)), acc.y);
  }
  float inv = 1.f / (den + ws + 1e-16f);

  // BN + ELU + both heads (lane holds features q*2, q*2+1)
  const int c0 = q << 1;
  float2 Sv = *(const float2*)&S2[c0];
  float2 Tv = *(const float2*)&T2[c0];
  float2 wr = *(const float2*)&Wr[c0];
  float2 wc = *(const float2*)&Wc[c0];
  float o0 = elu_fast(fmaf(acc.x, inv * Sv.x, Tv.x));
  float o1 = elu_fast(fmaf(acc.y, inv * Sv.y, Tv.y));
  float rs = o0 * wr.x + o1 * wr.y;
  float cs = o0 * wc.x + o1 * wc.y;
#pragma unroll
  for (int o = 1; o < 32; o <<= 1) {  // stays within the 32-lane half
    rs += __shfl_xor(rs, o, 64);
    cs += __shfl_xor(cs, o, 64);
  }
  if (q == 0 && valid) {
    out_reg[n] = rs + br[0];
    float z = cs + bc[0];
    out_clf[n] = 1.f / (1.f + __expf(-z));
  }
}

// ---------------- launcher ----------------
extern "C" void kernel_launch(void* const* d_in, const int* in_sizes, int n_in,
                              void* d_out, int out_size, void* d_ws, size_t ws_size,
                              hipStream_t stream) {
  const float* x      = (const float*)d_in[0];
  const int*   ei     = (const int*)d_in[1];
  const float* W1     = (const float*)d_in[2];
  const float* a_src1 = (const float*)d_in[3];
  const float* a_dst1 = (const float*)d_in[4];
  const float* b1     = (const float*)d_in[5];
  const float* bn1w   = (const float*)d_in[6];
  const float* bn1b   = (const float*)d_in[7];
  const float* bn1m   = (const float*)d_in[8];
  const float* bn1v   = (const float*)d_in[9];
  const float* W2     = (const float*)d_in[10];
  const float* a_src2 = (const float*)d_in[11];
  const float* a_dst2 = (const float*)d_in[12];
  const float* b2     = (const float*)d_in[13];
  const float* bn2w   = (const float*)d_in[14];
  const float* bn2b   = (const float*)d_in[15];
  const float* bn2m   = (const float*)d_in[16];
  const float* bn2v   = (const float*)d_in[17];
  const float* Wr     = (const float*)d_in[18];
  const float* br     = (const float*)d_in[19];
  const float* Wc     = (const float*)d_in[20];
  const float* bc     = (const float*)d_in[21];

  const int N = in_sizes[0] / 256;  // 50000
  const int E = in_sizes[1] / 2;    // 400000
  const int* srcv = ei;
  const int* dstv = ei + E;

  char* w = (char*)d_ws;
  auto alloc = [&](size_t bytes) {
    char* p = w;
    w += (bytes + 255) & ~(size_t)255;
    return p;
  };
  const int nb = (N + 255) / 256;  // 196 chunks of 256
  const size_t nbytes_rounded = ((size_t)N * 4 + 255) & ~(size_t)255;
  int* counts    = (int*)alloc((size_t)N * 4);
  int* cursor    = (int*)alloc((size_t)N * 4);  // contiguous with counts
  int* offsets   = (int*)alloc((size_t)N * 4);  // chunk-local scan
  int* offs2     = (int*)alloc((size_t)(N + 1) * 4);  // finalized
  int* partials  = (int*)alloc((size_t)nb * 4);
  int* csr_src   = (int*)alloc((size_t)(E + 64) * 4);  // +64 zero pad
  float* as1     = (float*)alloc((size_t)N * 4 * 4);
  float* ad1     = (float*)alloc((size_t)N * 4 * 4);
  float* as2     = (float*)alloc((size_t)N * 4);
  float* ad2     = (float*)alloc((size_t)N * 4);
  float* S1      = (float*)alloc(256 * 4);
  float* T1      = (float*)alloc(256 * 4);
  float* S2      = (float*)alloc(64 * 4);
  float* T2      = (float*)alloc(64 * 4);
  ushort_t* W1t  = (ushort_t*)alloc((size_t)256 * 256 * 2);
  ushort_t* W2t  = (ushort_t*)alloc((size_t)64 * 256 * 2);
  uchar_t* h1b   = (uchar_t*)alloc((size_t)N * 256);       // fp8 e4m3
  ushort_t* h1a  = (ushort_t*)alloc((size_t)N * 256 * 2);  // bf16
  ushort_t* h2b  = (ushort_t*)alloc((size_t)N * 64 * 2);   // bf16

  float* out_reg = (float*)d_out;

  // graph build (4 dispatches)
  hipMemsetAsync(counts, 0, nbytes_rounded * 2, stream);  // counts + cursor
  hist_kernel<<<(E + 255) / 256, 256, 0, stream>>>(dstv, counts, E);
  scan_chunks_kernel<<<nb, 256, 0, stream>>>(counts, offsets, partials, N, E, csr_src,
                                             W1, W2, W1t, W2t,
                                             b1, bn1w, bn1b, bn1m, bn1v,
                                             b2, bn2w, bn2b, bn2m, bn2v,
                                             S1, T1, S2, T2);
  {
    int items = max(E, N + 1);
    scatter_kernel<<<(items + 255) / 256, 256, 0, stream>>>(srcv, dstv, offsets, partials,
                                                            cursor, csr_src, offs2, E, N, nb);
  }

  const int nwb = (N + 3) / 4;
  const int nwb2 = (N + 7) / 8;
  const int ntiles1 = (N + 31) / 32;   // 1563
  const int mtiles2 = (N + 63) / 64;   // 782

  // layer 1 (gemm1: persistent-B, fp32 A direct, fp8 out)
  gemm1_persist<<<256, 512, 0, stream>>>(
      x, W1t, h1b, a_src1, a_dst1, as1, ad1, N, ntiles1);
  agg1_kernel<<<nwb, 256, 0, stream>>>(h1b, offs2, csr_src, as1, ad1, S1, T1, h1a, N);

  // layer 2 (gemm2: full-K, bf16 out)
  gemm2_fullk<<<mtiles2, 256, 0, stream>>>(
      h1a, W2t, h2b, a_src2, a_dst2, as2, ad2, N);
  agg2_kernel<<<nwb2, 256, 0, stream>>>(h2b, offs2, csr_src, as2, ad2, S2, T2,
                                        Wr, br, Wc, bc, out_reg, out_reg + N, N);
}